// Round 10
// baseline (820.140 us; speedup 1.0000x reference)
//
#include <hip/hip_runtime.h>

#define D 128
#define K 64
#define NROWS 200000
#define RT_ROWS 64
#define NTILES (NROWS / RT_ROWS)   // 3125
#define TPB 256
#define NBLK 512
#define TILE_BYTES 49152           // image: XH 16K | XL 16K | XT 16K
#define PSLOT2 8320                // K*D mean + K cluster_r, padded (floats)
#define SUB 16                     // atomic sub-slots per iteration
#define SLOT_STRIDE (SUB * PSLOT2)
#define NIT 11

typedef __attribute__((ext_vector_type(8))) short bf16x8;   // 8 bf16 = 4 VGPR
typedef __attribute__((ext_vector_type(4))) float f32x4;

// pass-kernel LDS arena (bytes): XH|XL contiguous 32K; XT double-buffered
#define XH  0
#define XL  16384
#define XT0 32768
#define XT1 49152
#define RTT 65536      // r^T [64 clusters][64 rows] bf16, swizzled (8K)
#define RSO 73728      // [4][64] f32 cluster_r wave partials (1K)
#define LDS_BYTES 74752

__device__ __forceinline__ int xrow_off(int row, int dim) {
  return (row * 256 + dim * 2) ^ ((row & 7) << 4);
}
__device__ __forceinline__ int xt_off(int dim, int row) {
  return (dim * 128 + row * 2) ^ ((dim & 7) << 4);
}
__device__ __forceinline__ int rt_off(int c, int row) {
  return (c * 128 + row * 2) ^ ((c & 7) << 4);
}
__device__ __forceinline__ ushort f2bf(float x) {   // round-to-nearest-even
  uint u = __float_as_uint(x);
  return (ushort)((u + 0x7FFF + ((u >> 16) & 1)) >> 16);
}
__device__ __forceinline__ float bf2f(ushort b) {
  return __uint_as_float(((uint)b) << 16);
}
__device__ __forceinline__ float dot4(const float4 a, const float4 b) {
  return a.x * b.x + a.y * b.y + a.z * b.z + a.w * b.w;
}
__device__ __forceinline__ void gload16(const char* g, char* l) {
  __builtin_amdgcn_global_load_lds(
      (__attribute__((address_space(1))) void*)(g),
      (__attribute__((address_space(3))) void*)(l), 16, 0, 0);
}

// ---------- prep (once): normalize X, bf16 hi/lo split; XH/XL images written
// ---------- straight from registers; XT via conflict-free LDS read-transpose.
__global__ __launch_bounds__(TPB) void prep_kernel(
    const float* __restrict__ data, char* __restrict__ prep)
{
  __shared__ __align__(16) char smem[16384];   // hi staging for transpose
  const int t = threadIdx.x;
  const int tile = blockIdx.x;
  const int row = t >> 2, d0 = (t & 3) * 32;   // 4 threads per row

  const float4* src = (const float4*)(data + (size_t)(tile * RT_ROWS + row) * D + d0);
  float xf[32];
  float ss = 0.f;
#pragma unroll
  for (int i = 0; i < 8; ++i) {
    float4 v = src[i];
    ss += dot4(v, v);
    xf[4 * i] = v.x; xf[4 * i + 1] = v.y; xf[4 * i + 2] = v.z; xf[4 * i + 3] = v.w;
  }
  ss += __shfl_xor(ss, 1);
  ss += __shfl_xor(ss, 2);
  const float inv = 1.f / (sqrtf(ss) + 1e-6f);

  char* gout = prep + (size_t)tile * TILE_BYTES;
#pragma unroll
  for (int j = 0; j < 4; ++j) {
    uint hp[4], lp[4];
#pragma unroll
    for (int q = 0; q < 4; ++q) {
      const float a0 = xf[8*j + 2*q] * inv, a1 = xf[8*j + 2*q + 1] * inv;
      const ushort h0 = f2bf(a0), h1 = f2bf(a1);
      const ushort g0 = f2bf(a0 - bf2f(h0)), g1 = f2bf(a1 - bf2f(h1));
      hp[q] = (uint)h0 | ((uint)h1 << 16);
      lp[q] = (uint)g0 | ((uint)g1 << 16);
    }
    const uint4 h4 = make_uint4(hp[0], hp[1], hp[2], hp[3]);
    const int off = xrow_off(row, d0 + 8*j);
    *(uint4*)(gout + off) = h4;                                    // XH image
    *(uint4*)(gout + 16384 + off) = make_uint4(lp[0], lp[1], lp[2], lp[3]);
    *(uint4*)(smem + off) = h4;                                    // LDS hi
  }
  __syncthreads();

  // transpose from LDS: thread -> dim = t&127, row-half = t>>7 (32 rows, 64B)
  {
    const int dim = t & 127, r0 = (t >> 7) * 32;
#pragma unroll
    for (int jj = 0; jj < 4; ++jj) {
      uint p[4];
#pragma unroll
      for (int q = 0; q < 4; ++q) {
        const ushort v0 = *(const ushort*)(smem + xrow_off(r0 + 8*jj + 2*q, dim));
        const ushort v1 = *(const ushort*)(smem + xrow_off(r0 + 8*jj + 2*q + 1, dim));
        p[q] = (uint)v0 | ((uint)v1 << 16);
      }
      *(uint4*)(gout + 32768 + xt_off(dim, r0 + 8*jj)) =
          make_uint4(p[0], p[1], p[2], p[3]);
    }
  }
}

// ---------- per-iteration pass: counted-vmcnt pipelined staging, dist MFMA
// ---------- (hi/lo split), softmax, r^T@X MFMA, 16-way-spread atomic output.
__global__ __launch_bounds__(TPB, 2) void pass_kernel(
    const char* __restrict__ prep, const float* __restrict__ mu_src,
    const int first, const int* __restrict__ temp_p,
    float* __restrict__ acc_slot, float* __restrict__ r_out, const int write_r)
{
  __shared__ __align__(16) char smem[LDS_BYTES];
  const int t = threadIdx.x;
  const int w = t >> 6, l = t & 63, lg = l >> 4, lr = l & 15;
  const float temp = (float)(*temp_p);

  // ---- prologue: merge 16 sub-slots (or read init), normalize mu
  // ---- (scale-invariant), bf16 hi/lo split staged in XT0/XT1 scratch.
  {
    const int row = t >> 2, d0 = (t & 3) * 32;
    float mf[32];
    if (first) {
      const float4* src = (const float4*)(mu_src + row * D + d0);
#pragma unroll
      for (int i = 0; i < 8; ++i) {
        float4 v = src[i];
        mf[4*i] = v.x; mf[4*i+1] = v.y; mf[4*i+2] = v.z; mf[4*i+3] = v.w;
      }
    } else {
#pragma unroll
      for (int e = 0; e < 32; ++e) mf[e] = 0.f;
      for (int s = 0; s < SUB; ++s) {
        const float4* p = (const float4*)(mu_src + s * PSLOT2 + row * D + d0);
#pragma unroll
        for (int i = 0; i < 8; ++i) {
          float4 v = p[i];
          mf[4*i] += v.x; mf[4*i+1] += v.y; mf[4*i+2] += v.z; mf[4*i+3] += v.w;
        }
      }
    }
    float ss = 0.f;
#pragma unroll
    for (int e = 0; e < 32; ++e) ss += mf[e] * mf[e];
    ss += __shfl_xor(ss, 1);
    ss += __shfl_xor(ss, 2);
    const float inv = 1.f / (sqrtf(ss) + 1e-6f);
#pragma unroll
    for (int j = 0; j < 4; ++j) {
      uint hp[4], lp[4];
#pragma unroll
      for (int q = 0; q < 4; ++q) {
        const float a0 = mf[8*j + 2*q] * inv, a1 = mf[8*j + 2*q + 1] * inv;
        const ushort h0 = f2bf(a0), h1 = f2bf(a1);
        const ushort g0 = f2bf(a0 - bf2f(h0)), g1 = f2bf(a1 - bf2f(h1));
        hp[q] = (uint)h0 | ((uint)h1 << 16);
        lp[q] = (uint)g0 | ((uint)g1 << 16);
      }
      const int off = xrow_off(row, d0 + 8*j);
      *(uint4*)(smem + XT0 + off) = make_uint4(hp[0], hp[1], hp[2], hp[3]);
      *(uint4*)(smem + XT1 + off) = make_uint4(lp[0], lp[1], lp[2], lp[3]);
    }
  }
  __syncthreads();
  bf16x8 muh[4][4], mul[4][4];
#pragma unroll
  for (int kc = 0; kc < 4; ++kc)
#pragma unroll
    for (int ns = 0; ns < 4; ++ns) {
      muh[kc][ns] = *(const bf16x8*)(smem + XT0 + xrow_off(16*ns + lr, kc*32 + lg*8));
      mul[kc][ns] = *(const bf16x8*)(smem + XT1 + xrow_off(16*ns + lr, kc*32 + lg*8));
    }
  __syncthreads();   // XT0/XT1 now free for staging

  f32x4 accm[4][2];
#pragma unroll
  for (int ms = 0; ms < 4; ++ms)
#pragma unroll
    for (int n2 = 0; n2 < 2; ++n2) accm[ms][n2] = (f32x4){0.f, 0.f, 0.f, 0.f};
  float rsum[4] = {0.f, 0.f, 0.f, 0.f};

  // ---- initial stage: XHXL(0) [8] then XT(0)->XT0 [4]
  asm volatile("s_waitcnt vmcnt(0)" ::: "memory");
  {
    const char* g0 = prep + (size_t)blockIdx.x * TILE_BYTES + w * 1024 + l * 16;
#pragma unroll
    for (int i = 0; i < 8; ++i) gload16(g0 + i * 4096, smem + XH + i * 4096 + w * 1024);
#pragma unroll
    for (int i = 0; i < 4; ++i) gload16(g0 + 32768 + i * 4096, smem + XT0 + i * 4096 + w * 1024);
  }
  int cur = 0;

  for (int tile = blockIdx.x; tile < NTILES; tile += NBLK) {
    int nxt = tile + NBLK;
    if (nxt >= NTILES) nxt = tile;          // dummy re-stage keeps counts uniform
    const char* gn = prep + (size_t)nxt * TILE_BYTES + w * 1024 + l * 16;

    // b0: XHXL(t) arrived (XT(t) may still fly)
    asm volatile("s_waitcnt vmcnt(4)" ::: "memory");
    __builtin_amdgcn_sched_barrier(0);
    __builtin_amdgcn_s_barrier();

    // ---- dist: rows 16w..16w+15, all 64 clusters; hi/lo split (3 MFMA) ----
    f32x4 pacc[4];
#pragma unroll
    for (int ns = 0; ns < 4; ++ns) pacc[ns] = (f32x4){0.f, 0.f, 0.f, 0.f};
#pragma unroll
    for (int kc = 0; kc < 4; ++kc) {
      const int doff = kc * 32 + lg * 8;
      const bf16x8 ah = *(const bf16x8*)(smem + XH + xrow_off(16*w + lr, doff));
      const bf16x8 al = *(const bf16x8*)(smem + XL + xrow_off(16*w + lr, doff));
#pragma unroll
      for (int ns = 0; ns < 4; ++ns) {
        pacc[ns] = __builtin_amdgcn_mfma_f32_16x16x32_bf16(ah, muh[kc][ns], pacc[ns], 0, 0, 0);
        pacc[ns] = __builtin_amdgcn_mfma_f32_16x16x32_bf16(al, muh[kc][ns], pacc[ns], 0, 0, 0);
        pacc[ns] = __builtin_amdgcn_mfma_f32_16x16x32_bf16(ah, mul[kc][ns], pacc[ns], 0, 0, 0);
      }
    }

    // ---- softmax over clusters (row = 16w + lg*4 + j; cluster = 16ns + lr)
    float rv[4][4], sinv[4];
#pragma unroll
    for (int j = 0; j < 4; ++j) {
      float sj = 0.f;
#pragma unroll
      for (int ns = 0; ns < 4; ++ns) { rv[ns][j] = __expf(temp * pacc[ns][j]); sj += rv[ns][j]; }
      sj += __shfl_xor(sj, 1); sj += __shfl_xor(sj, 2);
      sj += __shfl_xor(sj, 4); sj += __shfl_xor(sj, 8);
      sinv[j] = 1.f / sj;
    }
#pragma unroll
    for (int ns = 0; ns < 4; ++ns) {
      const float r0 = rv[ns][0]*sinv[0], r1 = rv[ns][1]*sinv[1],
                  r2 = rv[ns][2]*sinv[2], r3 = rv[ns][3]*sinv[3];
      const ushort h0 = f2bf(r0), h1 = f2bf(r1), h2 = f2bf(r2), h3 = f2bf(r3);
      rsum[ns] += (bf2f(h0) + bf2f(h1)) + (bf2f(h2) + bf2f(h3));
      *(uint2*)(smem + RTT + rt_off(16*ns + lr, 16*w + lg*4)) =
          make_uint2((uint)h0 | ((uint)h1 << 16), (uint)h2 | ((uint)h3 << 16));
      if (write_r) {
        const size_t rb = (size_t)tile * RT_ROWS + 16*w + lg*4;
        r_out[(rb + 0) * K + 16*ns + lr] = r0;
        r_out[(rb + 1) * K + 16*ns + lr] = r1;
        r_out[(rb + 2) * K + 16*ns + lr] = r2;
        r_out[(rb + 3) * K + 16*ns + lr] = r3;
      }
    }

    // b1: RTT visible; all waves done reading XHXL(t)
    asm volatile("s_waitcnt lgkmcnt(0)" ::: "memory");
    __builtin_amdgcn_sched_barrier(0);
    __builtin_amdgcn_s_barrier();

    // issue XHXL(t+1) over the dead XH/XL
#pragma unroll
    for (int i = 0; i < 8; ++i) gload16(gn + i * 4096, smem + XH + i * 4096 + w * 1024);

    // b2: XT(t) arrived (the 8 XHXL just issued may fly)
    asm volatile("s_waitcnt vmcnt(8)" ::: "memory");
    __builtin_amdgcn_sched_barrier(0);
    __builtin_amdgcn_s_barrier();

    // ---- accumulate cluster_mean += r^T @ Xn (wave w: dims 32w..32w+31) ----
    {
      char* xtc = smem + (cur ? XT1 : XT0);
#pragma unroll
      for (int kc2 = 0; kc2 < 2; ++kc2) {
        const int k0 = kc2 * 32 + lg * 8;
        bf16x8 af[4];
#pragma unroll
        for (int ms = 0; ms < 4; ++ms)
          af[ms] = *(const bf16x8*)(smem + RTT + rt_off(16*ms + lr, k0));
#pragma unroll
        for (int n2 = 0; n2 < 2; ++n2) {
          const int dim = 32*w + 16*n2 + lr;
          const bf16x8 bv = *(const bf16x8*)(xtc + xt_off(dim, k0));
#pragma unroll
          for (int ms = 0; ms < 4; ++ms)
            accm[ms][n2] = __builtin_amdgcn_mfma_f32_16x16x32_bf16(af[ms], bv, accm[ms][n2], 0, 0, 0);
        }
      }
    }

    // issue XT(t+1) into the other buffer (safe: barriers separate prev readers)
    {
      char* xtn = smem + (cur ? XT0 : XT1);
#pragma unroll
      for (int i = 0; i < 4; ++i) gload16(gn + 32768 + i * 4096, xtn + i * 4096 + w * 1024);
    }
    cur ^= 1;
  }

  // ---- epilogue: spread atomics over 16 sub-slots ----
  float* slot = acc_slot + (size_t)(blockIdx.x & (SUB - 1)) * PSLOT2;
#pragma unroll
  for (int ms = 0; ms < 4; ++ms)
#pragma unroll
    for (int n2 = 0; n2 < 2; ++n2)
#pragma unroll
      for (int j = 0; j < 4; ++j)
        atomicAdd(&slot[(16*ms + lg*4 + j) * D + 32*w + 16*n2 + lr], accm[ms][n2][j]);
#pragma unroll
  for (int ns = 0; ns < 4; ++ns) {
    rsum[ns] += __shfl_xor(rsum[ns], 16);
    rsum[ns] += __shfl_xor(rsum[ns], 32);
  }
  float* rs = (float*)(smem + RSO);
  if (lg == 0)
#pragma unroll
    for (int ns = 0; ns < 4; ++ns) rs[w * K + 16*ns + lr] = rsum[ns];
  __syncthreads();
  if (t < K)
    atomicAdd(&slot[K*D + t], (rs[t] + rs[K + t]) + (rs[2*K + t] + rs[3*K + t]));
}

// final mu output: sum 16 sub-slots, divide mean by cluster_r
__global__ __launch_bounds__(TPB) void final_kernel(
    const float* __restrict__ slot, float* __restrict__ mu_out)
{
  const int idx = blockIdx.x * TPB + threadIdx.x;   // 32 x 256 = 8192
  const int c = idx >> 7;
  float m = 0.f, r = 0.f;
#pragma unroll
  for (int s = 0; s < SUB; ++s) {
    m += slot[s * PSLOT2 + idx];
    r += slot[s * PSLOT2 + K * D + c];
  }
  mu_out[idx] = m / r;
}

extern "C" void kernel_launch(void* const* d_in, const int* in_sizes, int n_in,
                              void* d_out, int out_size, void* d_ws, size_t ws_size,
                              hipStream_t stream)
{
  const float* data = (const float*)d_in[0];   // [200000,128] f32
  const float* init = (const float*)d_in[1];   // [64,128] f32
  const int* temp_p = (const int*)d_in[2];     // scalar 30
  float* out = (float*)d_out;                  // [0,8192) mu, then r [200000,64]

  char* prep = (char*)d_ws;                                     // 153.6 MB
  float* slots = (float*)(prep + (size_t)NTILES * TILE_BYTES);  // 11 x 16 sub-slots

  hipMemsetAsync(slots, 0, (size_t)NIT * SLOT_STRIDE * sizeof(float), stream);
  prep_kernel<<<dim3(NTILES), dim3(TPB), 0, stream>>>(data, prep);

  // 10 iterations of _cluster#1 + 1 of _cluster#2 == 11 identical steps.
  // normalize(mean/r) == normalize(mean), so /cluster_r only at the end.
  for (int it = 0; it < NIT; ++it) {
    const float* mu_src = (it == 0) ? init : (slots + (size_t)(it - 1) * SLOT_STRIDE);
    pass_kernel<<<dim3(NBLK), dim3(TPB), 0, stream>>>(
        prep, mu_src, (it == 0) ? 1 : 0, temp_p,
        slots + (size_t)it * SLOT_STRIDE, out + K*D, (it == NIT - 1) ? 1 : 0);
  }
  final_kernel<<<dim3(32), dim3(TPB), 0, stream>>>(
      slots + (size_t)(NIT - 1) * SLOT_STRIDE, out);
}